// Round 1
// baseline (98.257 us; speedup 1.0000x reference)
//
#include <hip/hip_runtime.h>
#include <stdint.h>
#include <math.h>

#define T_SEQ 8192

typedef int vint4 __attribute__((ext_vector_type(4)));  // native vector: OK for nontemporal builtins

__device__ __forceinline__ uint32_t rotl32(uint32_t x, int n) {
    return (x << n) | (x >> (32 - n));
}

// JAX threefry2x32 with key = (0, 42) (jax.random.key(42)), counts = iota(12288)
// split in half: pair i -> (x0=i, x1=i+6144); bits[idx] = idx<6144 ? y0 : y1.
__device__ uint32_t jax_threefry_bits_12288(uint32_t idx) {
    const uint32_t k0 = 0u, k1 = 42u, k2 = 0u ^ 42u ^ 0x1BD11BDAu;
    uint32_t i = (idx < 6144u) ? idx : (idx - 6144u);
    uint32_t x0 = i + k0;
    uint32_t x1 = (i + 6144u) + k1;
#define TF_R4(a,b,c,d) \
    x0 += x1; x1 = rotl32(x1, a); x1 ^= x0; \
    x0 += x1; x1 = rotl32(x1, b); x1 ^= x0; \
    x0 += x1; x1 = rotl32(x1, c); x1 ^= x0; \
    x0 += x1; x1 = rotl32(x1, d); x1 ^= x0;
    TF_R4(13, 15, 26, 6);   x0 += k1; x1 += k2 + 1u;
    TF_R4(17, 29, 16, 24);  x0 += k2; x1 += k0 + 2u;
    TF_R4(13, 15, 26, 6);   x0 += k0; x1 += k1 + 3u;
    TF_R4(17, 29, 16, 24);  x0 += k1; x1 += k2 + 4u;
    TF_R4(13, 15, 26, 6);   x0 += k2; x1 += k0 + 5u;
#undef TF_R4
    return (idx < 6144u) ? x0 : x1;
}

// Fully fused: stats + 2-layer MLP. 2 rows per block, 512 threads (8 waves),
// 512 blocks = 2 blocks/CU = 16 waves/CU (measured-best grid config from prior session).
// R0 changes: (1) batch all 8 vint4 loads into registers BEFORE the atomic loop
// (forces back-to-back issue, one vmcnt drain, hides HBM latency under nothing
// but itself instead of serializing load->atomic->load);
// (2) half-wave-private histograms (16x128) to halve same-address atomic depth.
__global__ __launch_bounds__(512) void fused_kernel(const int* __restrict__ tok,
                                                    const float* __restrict__ W1,
                                                    const float* __restrict__ b1,
                                                    const float* __restrict__ W2,
                                                    const float* __restrict__ b2,
                                                    float* __restrict__ out) {
    const int tid = threadIdx.x;
    const int wave = tid >> 6;
    const int hw = tid >> 5;        // half-wave id 0..15 (private histogram per 32 lanes)
    const int r0 = blockIdx.x * 2;

    __shared__ int hist[16][128];
    __shared__ int wsum[8];
    __shared__ unsigned wsq[8];
    __shared__ float s[2][150];    // stats rows
    __shared__ float h[2][256];    // hidden layer
    __shared__ float part[2][128]; // layer-2 split-k partials (upper half)

    // zero histograms (2048 ints, 4 per thread)
    for (int i = tid; i < 2048; i += 512) ((int*)hist)[i] = 0;
    __syncthreads();

    // ---- phase 1: token stream -> hist / sum / sumsq ----
    {
        const int row_local = tid >> 8;   // 0 or 1
        const int t256 = tid & 255;       // thread id within the row's 256-thread group
        const vint4* tp = (const vint4*)(tok + (size_t)(r0 + row_local) * T_SEQ);

        // batch-load: 8x global_load_dwordx4 issued back-to-back (32 VGPRs),
        // static indices only (full unroll) so the array stays in registers.
        vint4 v[8];
#pragma unroll
        for (int j = 0; j < 8; ++j)
            v[j] = __builtin_nontemporal_load(&tp[j * 256 + t256]); // single-use stream

        int sum = 0;
        unsigned sq = 0;
#pragma unroll
        for (int j = 0; j < 8; ++j) {
            atomicAdd(&hist[hw][v[j].x & 127], 1); sum += v[j].x; sq += (unsigned)__mul24(v[j].x, v[j].x);
            atomicAdd(&hist[hw][v[j].y & 127], 1); sum += v[j].y; sq += (unsigned)__mul24(v[j].y, v[j].y);
            atomicAdd(&hist[hw][v[j].z & 127], 1); sum += v[j].z; sq += (unsigned)__mul24(v[j].z, v[j].z);
            atomicAdd(&hist[hw][v[j].w & 127], 1); sum += v[j].w; sq += (unsigned)__mul24(v[j].w, v[j].w);
        }
        // 64-lane wave reduction; both sums fit in 32 bits (max sumsq ~1.25e9 < 2^31)
#pragma unroll
        for (int off = 32; off > 0; off >>= 1) {
            sum += __shfl_down(sum, off);
            sq  += __shfl_down(sq, off);
        }
        if ((tid & 63) == 0) { wsum[wave] = sum; wsq[wave] = sq; }
    }
    __syncthreads();

    // ---- stats assembly into LDS (300 active threads: 2 rows x 150 dims) ----
    if (tid < 300) {
        const int r = tid >= 150;
        const int k = tid - r * 150;
        const int wb = r * 4;      // wave base for wsum/wsq
        const int hb = r * 8;      // half-wave base for hist
        float val;
        if (k < 128) {
            int hh = (hist[hb][k] + hist[hb + 1][k]) + (hist[hb + 2][k] + hist[hb + 3][k])
                   + (hist[hb + 4][k] + hist[hb + 5][k]) + (hist[hb + 6][k] + hist[hb + 7][k]);
            // reference divisor (8192.0f + 1e-8f) == 8192.0f exactly in fp32
            val = (float)hh * (1.0f / 8192.0f);
        } else if (k == 128) {
            int ss = wsum[wb] + wsum[wb + 1] + wsum[wb + 2] + wsum[wb + 3];
            val = (float)ss * (1.0f / 8192.0f);  // exact: ss < 2^24, / 2^13
        } else if (k == 129) {
            double ss = (double)(wsum[wb] + wsum[wb + 1] + wsum[wb + 2] + wsum[wb + 3]);
            double qq = (double)wsq[wb] + (double)wsq[wb + 1] + (double)wsq[wb + 2] + (double)wsq[wb + 3];
            val = (float)sqrt((qq - ss * ss / 8192.0) / 8191.0);  // unbiased (T-1)
        } else if (k < 138) {
            val = 0.0f;  // rhythm dims 2..9
        } else {
            uint32_t bits = jax_threefry_bits_12288((uint32_t)(r0 + r) * 12u + (uint32_t)(k - 138));
            val = __uint_as_float((bits >> 9) | 0x3f800000u) - 1.0f;
        }
        s[r][k] = val;
    }
    __syncthreads();

    // ---- phase 2: layer 1 (512 threads = 2 rows x 256 cols) ----
    {
        const int g = tid >> 8, c = tid & 255;
        float acc = b1[c];
#pragma unroll 5
        for (int k = 0; k < 150; ++k)
            acc = fmaf(s[g][k], W1[k * 256 + c], acc);  // s broadcast, W1 coalesced
        h[g][c] = fmaxf(acc, 0.0f);
    }
    __syncthreads();

    // ---- phase 3: layer 2, split-k over 2 halves (512 threads = 2x2x128) ----
    {
        const int half = tid >> 8, g = (tid >> 7) & 1, c = tid & 127;
        const float* hr = h[g];
        const int kb = half * 128;
        float acc = half ? 0.0f : b2[c];
#pragma unroll 8
        for (int k = 0; k < 128; ++k)
            acc = fmaf(hr[kb + k], W2[(kb + k) * 128 + c], acc);
        if (half) part[g][c] = acc;
        __syncthreads();
        if (!half) out[(r0 + g) * 128 + c] = acc + part[g][c];
    }
}

extern "C" void kernel_launch(void* const* d_in, const int* in_sizes, int n_in,
                              void* d_out, int out_size, void* d_ws, size_t ws_size,
                              hipStream_t stream) {
    const int*   tok = (const int*)d_in[0];
    const float* W1  = (const float*)d_in[1];
    const float* b1  = (const float*)d_in[2];
    const float* W2  = (const float*)d_in[3];
    const float* b2  = (const float*)d_in[4];
    float* out = (float*)d_out;

    fused_kernel<<<512, 512, 0, stream>>>(tok, W1, b1, W2, b2, out);
}